// Round 1
// baseline (1493.400 us; speedup 1.0000x reference)
//
#include <hip/hip_runtime.h>
#include <hip/hip_cooperative_groups.h>

namespace cg = cooperative_groups;

typedef __attribute__((ext_vector_type(8))) short short8;
typedef __attribute__((ext_vector_type(4))) short short4v;
typedef __attribute__((ext_vector_type(4))) float floatx4;

#define B_   128
#define D_   512
#define V_   10000
#define T_   20
#define G4   2048
#define VPAD 10112
#define KP2  10240
#define BD   (B_*D_)

__device__ __forceinline__ unsigned short f2b(float x){
  union { float f; unsigned u; } c; c.f = x;
  unsigned u = c.u;
  unsigned r = (u + 0x7fffu + ((u>>16)&1u)) >> 16;
  return (unsigned short)r;
}
__device__ __forceinline__ float sigm(float x){ return 1.0f/(1.0f+__expf(-x)); }

__global__ void k_convert(const float* __restrict__ src, unsigned short* __restrict__ dst, int n){
  int i = blockIdx.x*256 + threadIdx.x;
  if (i < n) dst[i] = f2b(src[i]);
}

__global__ void k_zero(float* p, int n){
  int i = blockIdx.x*256 + threadIdx.x;
  if (i < n) p[i] = 0.f;
}

__global__ void k_addvec(const float* __restrict__ a, const float* __restrict__ b,
                         float* __restrict__ d, int n){
  int i = blockIdx.x*256 + threadIdx.x;
  if (i < n) d[i] = a[i] + b[i];
}

// Transpose+convert W_enc (10000x512 fp32) into:
//   Wenc_b  [VPAD][512]  bf16 (row-major, for out_gemm; rows >=10000 zero)
//   WencT_b [512][KP2]   bf16 (K-major, for fold_gemm; cols >=10000 zero)
__global__ __launch_bounds__(256) void k_trans(const float* __restrict__ Wenc,
    unsigned short* __restrict__ Wenc_b, unsigned short* __restrict__ WencT){
  __shared__ short T[64*72];
  int tid = threadIdx.x;
  int v0 = blockIdx.x * 64;      // 160 tiles over KP2
  int d0 = blockIdx.y * 64;      // 8 tiles over 512
  #pragma unroll
  for (int i=0;i<4;i++){
    int s = tid + 256*i;          // 1024 slots: 64 rows x 16 float4
    int row = s >> 4, fq = s & 15;
    int v = v0 + row, d = d0 + fq*4;
    float4 f = {0.f,0.f,0.f,0.f};
    if (v < V_) f = *(const float4*)(Wenc + (long)v*D_ + d);
    short4v h; h[0]=(short)f2b(f.x); h[1]=(short)f2b(f.y); h[2]=(short)f2b(f.z); h[3]=(short)f2b(f.w);
    *(short4v*)(&T[row*72 + fq*4]) = h;
    if (v < VPAD) *(short4v*)(Wenc_b + (long)v*D_ + d) = h;
  }
  __syncthreads();
  #pragma unroll
  for (int i=0;i<2;i++){
    int s = tid + 256*i;          // 512 slots: 64 d-rows x 8 short8
    int drow = s >> 3, oct = s & 7;
    short8 v8;
    #pragma unroll
    for (int j=0;j<8;j++) v8[j] = T[(oct*8+j)*72 + drow];
    *(short8*)(WencT + (long)(d0+drow)*KP2 + v0 + oct*8) = v8;
  }
}

// bfold[g] = b_ih0[g]+b_hh0[g] + sum_v W_ih0[g][v]*b_enc[v]; biasA0 = b_ih0+b_hh0
__global__ void k_bias_fold(const float* __restrict__ Wih0, const float* __restrict__ b_enc,
                            const float* __restrict__ b_ih0, const float* __restrict__ b_hh0,
                            float* __restrict__ biasA0, float* __restrict__ bfold){
  __shared__ float red[256];
  int g = blockIdx.x;
  const float* row = Wih0 + (long)g*V_;
  float s = 0.f;
  for (int v = threadIdx.x; v < V_; v += 256) s += row[v]*b_enc[v];
  red[threadIdx.x] = s; __syncthreads();
  for (int w = 128; w >= 1; w >>= 1){
    if (threadIdx.x < w) red[threadIdx.x] += red[threadIdx.x+w];
    __syncthreads();
  }
  if (threadIdx.x == 0){
    float ba = b_ih0[g] + b_hh0[g];
    biasA0[g] = ba;
    bfold[g]  = ba + red[0];
  }
}

// Mf32 (2048x512 fp32, atomically accumulated) += W_ih0 (fp32, inline bf16) @ WencT^T
// Grid: 8 ksplits x 16 m-blocks x 4 n-blocks = 512 blocks; 128x128 tile, K=1280 each.
__global__ __launch_bounds__(256) void k_fold_gemm(const float* __restrict__ A,
                 const unsigned short* __restrict__ BT, float* __restrict__ Mf32){
  __shared__ short At[128*40];
  __shared__ short Bt[128*40];
  int tid = threadIdx.x;
  int b = blockIdx.x;
  int ks = b >> 6, mn = b & 63;
  int bm = mn >> 2, bn = mn & 3;
  int m0 = bm*128, n0 = bn*128, kb = ks*1280;
  int lane = tid&63, wave = tid>>6, l15 = lane&15, quad = lane>>4;
  int wm = (wave>>1)*64, wn = (wave&1)*64;
  floatx4 acc[4][4];
  #pragma unroll
  for (int i=0;i<4;i++)
    #pragma unroll
    for(int j=0;j<4;j++){ floatx4 z = {0.f,0.f,0.f,0.f}; acc[i][j] = z; }
  for (int it = 0; it < 40; it++){
    int k0 = kb + it*32;
    #pragma unroll
    for (int i=0;i<2;i++){
      int slot = tid + 256*i;           // 512 slots: 128 rows x 4 octs
      int row = slot >> 2, oct = slot & 3;
      const float* src = A + (long)(m0+row)*V_ + k0 + oct*8;
      short8 v;
      if (k0 + 32 <= V_){
        float4 f0 = *(const float4*)src;
        float4 f1 = *(const float4*)(src+4);
        v[0]=(short)f2b(f0.x); v[1]=(short)f2b(f0.y); v[2]=(short)f2b(f0.z); v[3]=(short)f2b(f0.w);
        v[4]=(short)f2b(f1.x); v[5]=(short)f2b(f1.y); v[6]=(short)f2b(f1.z); v[7]=(short)f2b(f1.w);
      } else {
        #pragma unroll
        for (int j=0;j<8;j++){
          int kk = k0 + oct*8 + j;
          float x = (kk < V_) ? src[j] : 0.f;
          v[j] = (short)f2b(x);
        }
      }
      *(short8*)(&At[row*40 + oct*8]) = v;
    }
    #pragma unroll
    for (int i=0;i<2;i++){
      int slot = tid + 256*i;
      int row = slot >> 2, oct = slot & 3;
      *(short8*)(&Bt[row*40 + oct*8]) = *(const short8*)(BT + (long)(n0+row)*KP2 + k0 + oct*8);
    }
    __syncthreads();
    short8 af[4], bf[4];
    #pragma unroll
    for (int i=0;i<4;i++){
      af[i] = *(const short8*)(&At[(wm + i*16 + l15)*40 + quad*8]);
      bf[i] = *(const short8*)(&Bt[(wn + i*16 + l15)*40 + quad*8]);
    }
    #pragma unroll
    for (int mi=0;mi<4;mi++)
      #pragma unroll
      for (int ni=0;ni<4;ni++)
        acc[mi][ni] = __builtin_amdgcn_mfma_f32_16x16x32_bf16(af[mi],bf[ni],acc[mi][ni],0,0,0);
    __syncthreads();
  }
  #pragma unroll
  for (int mi=0;mi<4;mi++)
    #pragma unroll
    for (int ni=0;ni<4;ni++){
      int n = n0 + wn + ni*16 + l15;
      #pragma unroll
      for (int r=0;r<4;r++){
        int m = m0 + wm + mi*16 + quad*4 + r;
        atomicAdd(&Mf32[(long)m*D_ + n], acc[mi][ni][r]);
      }
    }
}

// One LSTM layer-phase: gates(32x(16j x 4gates)) = ha@WA^T + hb@WB^T + bias, pointwise.
// Same math as the previous k_lstm kernel; c lives in registers (creg[2]) across calls.
__device__ __forceinline__ void lstm_phase(
    const unsigned short* __restrict__ ha, const unsigned short* __restrict__ WA,
    const unsigned short* __restrict__ hb, const unsigned short* __restrict__ WB,
    const float* __restrict__ bias, float* __restrict__ creg,
    unsigned short* __restrict__ hout, short* smem,
    int br0, int j0, int tid)
{
  short* Aa = smem;                      // [32][72]
  short* Ab = smem + 32*72;              // [32][72]
  short* Ba = smem + 2*32*72;            // [64][72]
  short* Bb = smem + 2*32*72 + 64*72;    // [64][72]
  int lane = tid & 63, wave = tid >> 6;
  int l15 = lane & 15, quad = lane >> 4;
  bool fA = (ha != nullptr), fB = (hb != nullptr);
  floatx4 acc[2];
  #pragma unroll
  for (int i=0;i<2;i++){ floatx4 z = {0.f,0.f,0.f,0.f}; acc[i] = z; }

  for (int k0 = 0; k0 < 512; k0 += 64){
    {
      int row = tid >> 3, oct = tid & 7;          // 256 slots: 32 rows x 8 octs
      if (fA) *(short8*)(&Aa[row*72+oct*8]) = *(const short8*)(ha + (br0+row)*512 + k0 + oct*8);
      if (fB) *(short8*)(&Ab[row*72+oct*8]) = *(const short8*)(hb + (br0+row)*512 + k0 + oct*8);
    }
    #pragma unroll
    for (int i=0;i<2;i++){
      int slot = tid + 256*i;                     // 512 slots: 64 rows x 8 octs
      int row = slot >> 3, oct = slot & 7;
      int g = (row>>4)*512 + j0 + (row&15);
      if (fA) *(short8*)(&Ba[row*72+oct*8]) = *(const short8*)(WA + (long)g*512 + k0 + oct*8);
      if (fB) *(short8*)(&Bb[row*72+oct*8]) = *(const short8*)(WB + (long)g*512 + k0 + oct*8);
    }
    __syncthreads();
    #pragma unroll
    for (int kk=0; kk<2; kk++){
      if (fA){
        short8 b = *(const short8*)(&Ba[(wave*16 + l15)*72 + kk*32 + quad*8]);
        #pragma unroll
        for (int mt=0; mt<2; mt++){
          short8 a = *(const short8*)(&Aa[(mt*16 + l15)*72 + kk*32 + quad*8]);
          acc[mt] = __builtin_amdgcn_mfma_f32_16x16x32_bf16(a,b,acc[mt],0,0,0);
        }
      }
      if (fB){
        short8 b = *(const short8*)(&Bb[(wave*16 + l15)*72 + kk*32 + quad*8]);
        #pragma unroll
        for (int mt=0; mt<2; mt++){
          short8 a = *(const short8*)(&Ab[(mt*16 + l15)*72 + kk*32 + quad*8]);
          acc[mt] = __builtin_amdgcn_mfma_f32_16x16x32_bf16(a,b,acc[mt],0,0,0);
        }
      }
    }
    __syncthreads();
  }
  // exchange gates through LDS: ex[gate][b_local][jj]
  float* ex = (float*)smem;    // 4*32*16 floats = 8 KB
  #pragma unroll
  for (int mt=0; mt<2; mt++)
    #pragma unroll
    for (int r=0;r<4;r++)
      ex[wave*512 + (mt*16 + quad*4 + r)*16 + l15] = acc[mt][r];
  __syncthreads();
  #pragma unroll
  for (int i=0;i<2;i++){
    int e = tid + 256*i;                 // 512 elems: 32 b x 16 j
    int bl = e >> 4, jj = e & 15;
    int b = br0 + bl, j = j0 + jj;
    float gi = ex[0*512 + bl*16 + jj] + bias[j];
    float gf = ex[1*512 + bl*16 + jj] + bias[512+j];
    float gg = ex[2*512 + bl*16 + jj] + bias[1024+j];
    float go = ex[3*512 + bl*16 + jj] + bias[1536+j];
    float ig = sigm(gi), fg = sigm(gf), gt = tanhf(gg), og = sigm(go);
    float cold = creg[i];
    float cn = fg*cold + ig*gt;
    creg[i] = cn;
    hout[b*512 + j] = f2b(og*tanhf(cn));
  }
}

// Persistent cooperative kernel: all T_=20 steps x 2 layers in one dispatch,
// grid.sync() between phases. Grid MUST be 128 blocks x 256 threads.
// Block mapping: jg = low 5 bits (col-group), bs = high 2 bits (batch-split)
// so that round-robin block->XCD assignment gives each XCD few unique
// weight col-groups (better L2 residency).
__global__ __launch_bounds__(256) void k_lstm_all(
    const unsigned short* __restrict__ Mfold, const unsigned short* __restrict__ Whh0,
    const unsigned short* __restrict__ Wih1, const unsigned short* __restrict__ Whh1,
    const float* __restrict__ biasA0, const float* __restrict__ bfold,
    const float* __restrict__ bias1,
    unsigned short* __restrict__ h0b0, unsigned short* __restrict__ h0b1,
    unsigned short* __restrict__ Hs)
{
  __shared__ short smem[13824];          // 27648 B
  cg::grid_group grid = cg::this_grid();
  int tid = threadIdx.x;
  int jg = blockIdx.x & 31, bs = blockIdx.x >> 5;
  int br0 = bs*32, j0 = jg*16;
  float cr0[2] = {0.f, 0.f};
  float cr1[2] = {0.f, 0.f};
  unsigned short* hc = h0b0;             // current h0 (holds converted input at t=0)
  unsigned short* hn = h0b1;
  for (int t = 0; t < T_; t++){
    const unsigned short* h1p = (t==0) ? nullptr : (Hs + (size_t)(t-1)*BD);
    // layer 0: gates = h1[t-1]@Mfold^T + h0[t-1]@Whh0^T + bias
    lstm_phase(h1p, Mfold, hc, Whh0, (t==0)?biasA0:bfold, cr0, hn, smem, br0, j0, tid);
    grid.sync();
    // layer 1: gates = h0[t]@Wih1^T + h1[t-1]@Whh1^T + bias1
    lstm_phase(hn, Wih1, h1p, Whh1, bias1, cr1, Hs + (size_t)t*BD, smem, br0, j0, tid);
    grid.sync();
    unsigned short* tmp = hc; hc = hn; hn = tmp;
  }
}

// Out = Hs (2560x512 bf16) @ Wenc_b^T (+b_enc) -> fp32 (2560x10000)
__global__ __launch_bounds__(256) void k_out_gemm(
    const unsigned short* __restrict__ Ah,
    const unsigned short* __restrict__ Bw,
    const float* __restrict__ b_enc, float* __restrict__ out)
{
  __shared__ short At[128*40];
  __shared__ short Bt[128*40];
  int tid = threadIdx.x;
  int bm = blockIdx.x % 20, bn = blockIdx.x / 20;
  int m0 = bm*128, n0 = bn*128;
  int lane = tid&63, wave = tid>>6, l15 = lane&15, quad = lane>>4;
  int wm = (wave>>1)*64, wn = (wave&1)*64;
  floatx4 acc[4][4];
  #pragma unroll
  for (int i=0;i<4;i++)
    #pragma unroll
    for(int j=0;j<4;j++){ floatx4 z = {0.f,0.f,0.f,0.f}; acc[i][j] = z; }
  for (int k0=0;k0<512;k0+=32){
    #pragma unroll
    for (int i=0;i<2;i++){
      int cc = tid + 256*i; int row = cc>>2; int ko=(cc&3)*8;
      *(short8*)(&At[row*40+ko]) = *(const short8*)(Ah + (long)(m0+row)*512 + k0+ko);
      *(short8*)(&Bt[row*40+ko]) = *(const short8*)(Bw + (long)(n0+row)*512 + k0+ko);
    }
    __syncthreads();
    short8 af[4], bf[4];
    #pragma unroll
    for (int i=0;i<4;i++){
      af[i] = *(const short8*)(&At[(wm + i*16 + l15)*40 + quad*8]);
      bf[i] = *(const short8*)(&Bt[(wn + i*16 + l15)*40 + quad*8]);
    }
    #pragma unroll
    for (int mi=0;mi<4;mi++)
      #pragma unroll
      for (int ni=0;ni<4;ni++)
        acc[mi][ni] = __builtin_amdgcn_mfma_f32_16x16x32_bf16(af[mi],bf[ni],acc[mi][ni],0,0,0);
    __syncthreads();
  }
  #pragma unroll
  for (int mi=0;mi<4;mi++)
    #pragma unroll
    for (int ni=0;ni<4;ni++){
      int n = n0 + wn + ni*16 + l15;
      if (n < V_){
        float be = b_enc[n];
        #pragma unroll
        for (int r=0;r<4;r++){
          int m = m0 + wm + mi*16 + quad*4 + r;
          out[(long)m*V_ + n] = acc[mi][ni][r] + be;
        }
      }
    }
}

extern "C" void kernel_launch(void* const* d_in, const int* in_sizes, int n_in,
                              void* d_out, int out_size, void* d_ws, size_t ws_size,
                              hipStream_t stream){
  const float* input_ = (const float*)d_in[0];
  const float* W_ih0  = (const float*)d_in[1];
  const float* W_hh0  = (const float*)d_in[2];
  const float* b_ih0  = (const float*)d_in[3];
  const float* b_hh0  = (const float*)d_in[4];
  const float* W_ih1  = (const float*)d_in[5];
  const float* W_hh1  = (const float*)d_in[6];
  const float* b_ih1  = (const float*)d_in[7];
  const float* b_hh1  = (const float*)d_in[8];
  const float* W_enc  = (const float*)d_in[9];
  const float* b_enc  = (const float*)d_in[10];
  float* out = (float*)d_out;

  char* ws = (char*)d_ws;
  size_t off = 0;
  auto alloc = [&](size_t bytes){ void* p = ws + off; off += (bytes + 255) & ~255ull; return p; };
  unsigned short* Wenc_b  = (unsigned short*)alloc((size_t)VPAD*512*2);
  unsigned short* WencT_b = (unsigned short*)alloc((size_t)512*KP2*2);
  float*          Mf32    = (float*)alloc((size_t)G4*512*4);
  unsigned short* Mfold_b = (unsigned short*)alloc((size_t)G4*512*2);
  unsigned short* Whh0_b  = (unsigned short*)alloc((size_t)G4*512*2);
  unsigned short* Wih1_b  = (unsigned short*)alloc((size_t)G4*512*2);
  unsigned short* Whh1_b  = (unsigned short*)alloc((size_t)G4*512*2);
  unsigned short* Hs_b    = (unsigned short*)alloc((size_t)T_*BD*2);
  unsigned short* h0b0    = (unsigned short*)alloc((size_t)BD*2);
  unsigned short* h0b1    = (unsigned short*)alloc((size_t)BD*2);
  float* biasA0 = (float*)alloc(2048*4);
  float* bfold  = (float*)alloc(2048*4);
  float* bias1  = (float*)alloc(2048*4);

  k_trans<<<dim3(KP2/64, 512/64), 256, 0, stream>>>(W_enc, Wenc_b, WencT_b);
  k_convert<<<(G4*512+255)/256, 256, 0, stream>>>(W_hh0, Whh0_b, G4*512);
  k_convert<<<(G4*512+255)/256, 256, 0, stream>>>(W_ih1, Wih1_b, G4*512);
  k_convert<<<(G4*512+255)/256, 256, 0, stream>>>(W_hh1, Whh1_b, G4*512);
  k_convert<<<(BD+255)/256, 256, 0, stream>>>(input_, h0b0, BD);
  k_zero<<<(G4*512+255)/256, 256, 0, stream>>>(Mf32, G4*512);
  k_addvec<<<8, 256, 0, stream>>>(b_ih1, b_hh1, bias1, 2048);
  k_bias_fold<<<2048, 256, 0, stream>>>(W_ih0, b_enc, b_ih0, b_hh0, biasA0, bfold);
  k_fold_gemm<<<512, 256, 0, stream>>>(W_ih0, WencT_b, Mf32);
  k_convert<<<(G4*512+255)/256, 256, 0, stream>>>(Mf32, Mfold_b, G4*512);

  {
    const unsigned short* a0 = Mfold_b; const unsigned short* a1 = Whh0_b;
    const unsigned short* a2 = Wih1_b; const unsigned short* a3 = Whh1_b;
    const float* a4 = biasA0; const float* a5 = bfold; const float* a6 = bias1;
    unsigned short* a7 = h0b0; unsigned short* a8 = h0b1; unsigned short* a9 = Hs_b;
    void* args[] = {&a0,&a1,&a2,&a3,&a4,&a5,&a6,&a7,&a8,&a9};
    hipLaunchCooperativeKernel((void*)k_lstm_all, dim3(128), dim3(256), args, 0u, stream);
  }

  k_out_gemm<<<20*79, 256, 0, stream>>>(Hs_b, Wenc_b, b_enc, out);
}

// Round 2
// 1017.633 us; speedup vs baseline: 1.4675x; 1.4675x over previous
//
#include <hip/hip_runtime.h>

typedef __attribute__((ext_vector_type(8))) short short8;
typedef __attribute__((ext_vector_type(4))) short short4v;
typedef __attribute__((ext_vector_type(4))) float floatx4;

#define B_   128
#define D_   512
#define V_   10000
#define T_   20
#define G4   2048
#define VPAD 10112
#define KP2  10240
#define BD   (B_*D_)
#define NBLK 128

__device__ __forceinline__ unsigned short f2b(float x){
  union { float f; unsigned u; } c; c.f = x;
  unsigned u = c.u;
  unsigned r = (u + 0x7fffu + ((u>>16)&1u)) >> 16;
  return (unsigned short)r;
}
__device__ __forceinline__ float sigm(float x){ return 1.0f/(1.0f+__expf(-x)); }

__global__ void k_convert(const float* __restrict__ src, unsigned short* __restrict__ dst, int n){
  int i = blockIdx.x*256 + threadIdx.x;
  if (i < n) dst[i] = f2b(src[i]);
}

__global__ void k_zero(float* p, int n){
  int i = blockIdx.x*256 + threadIdx.x;
  if (i < n) p[i] = 0.f;
}

__global__ void k_addvec(const float* __restrict__ a, const float* __restrict__ b,
                         float* __restrict__ d, int n){
  int i = blockIdx.x*256 + threadIdx.x;
  if (i < n) d[i] = a[i] + b[i];
}

// Transpose+convert W_enc (10000x512 fp32) into:
//   Wenc_b  [VPAD][512]  bf16 (row-major, for out_gemm; rows >=10000 zero)
//   WencT_b [512][KP2]   bf16 (K-major, for fold_gemm; cols >=10000 zero)
__global__ __launch_bounds__(256) void k_trans(const float* __restrict__ Wenc,
    unsigned short* __restrict__ Wenc_b, unsigned short* __restrict__ WencT){
  __shared__ short T[64*72];
  int tid = threadIdx.x;
  int v0 = blockIdx.x * 64;      // 160 tiles over KP2
  int d0 = blockIdx.y * 64;      // 8 tiles over 512
  #pragma unroll
  for (int i=0;i<4;i++){
    int s = tid + 256*i;          // 1024 slots: 64 rows x 16 float4
    int row = s >> 4, fq = s & 15;
    int v = v0 + row, d = d0 + fq*4;
    float4 f = {0.f,0.f,0.f,0.f};
    if (v < V_) f = *(const float4*)(Wenc + (long)v*D_ + d);
    short4v h; h[0]=(short)f2b(f.x); h[1]=(short)f2b(f.y); h[2]=(short)f2b(f.z); h[3]=(short)f2b(f.w);
    *(short4v*)(&T[row*72 + fq*4]) = h;
    if (v < VPAD) *(short4v*)(Wenc_b + (long)v*D_ + d) = h;
  }
  __syncthreads();
  #pragma unroll
  for (int i=0;i<2;i++){
    int s = tid + 256*i;          // 512 slots: 64 d-rows x 8 short8
    int drow = s >> 3, oct = s & 7;
    short8 v8;
    #pragma unroll
    for (int j=0;j<8;j++) v8[j] = T[(oct*8+j)*72 + drow];
    *(short8*)(WencT + (long)(d0+drow)*KP2 + v0 + oct*8) = v8;
  }
}

// bfold[g] = b_ih0[g]+b_hh0[g] + sum_v W_ih0[g][v]*b_enc[v]; biasA0 = b_ih0+b_hh0
__global__ void k_bias_fold(const float* __restrict__ Wih0, const float* __restrict__ b_enc,
                            const float* __restrict__ b_ih0, const float* __restrict__ b_hh0,
                            float* __restrict__ biasA0, float* __restrict__ bfold){
  __shared__ float red[256];
  int g = blockIdx.x;
  const float* row = Wih0 + (long)g*V_;
  float s = 0.f;
  for (int v = threadIdx.x; v < V_; v += 256) s += row[v]*b_enc[v];
  red[threadIdx.x] = s; __syncthreads();
  for (int w = 128; w >= 1; w >>= 1){
    if (threadIdx.x < w) red[threadIdx.x] += red[threadIdx.x+w];
    __syncthreads();
  }
  if (threadIdx.x == 0){
    float ba = b_ih0[g] + b_hh0[g];
    biasA0[g] = ba;
    bfold[g]  = ba + red[0];
  }
}

// Mf32 (2048x512 fp32, atomically accumulated) += W_ih0 (fp32, inline bf16) @ WencT^T
__global__ __launch_bounds__(256) void k_fold_gemm(const float* __restrict__ A,
                 const unsigned short* __restrict__ BT, float* __restrict__ Mf32){
  __shared__ short At[128*40];
  __shared__ short Bt[128*40];
  int tid = threadIdx.x;
  int b = blockIdx.x;
  int ks = b >> 6, mn = b & 63;
  int bm = mn >> 2, bn = mn & 3;
  int m0 = bm*128, n0 = bn*128, kb = ks*1280;
  int lane = tid&63, wave = tid>>6, l15 = lane&15, quad = lane>>4;
  int wm = (wave>>1)*64, wn = (wave&1)*64;
  floatx4 acc[4][4];
  #pragma unroll
  for (int i=0;i<4;i++)
    #pragma unroll
    for(int j=0;j<4;j++){ floatx4 z = {0.f,0.f,0.f,0.f}; acc[i][j] = z; }
  for (int it = 0; it < 40; it++){
    int k0 = kb + it*32;
    #pragma unroll
    for (int i=0;i<2;i++){
      int slot = tid + 256*i;           // 512 slots: 128 rows x 4 octs
      int row = slot >> 2, oct = slot & 3;
      const float* src = A + (long)(m0+row)*V_ + k0 + oct*8;
      short8 v;
      if (k0 + 32 <= V_){
        float4 f0 = *(const float4*)src;
        float4 f1 = *(const float4*)(src+4);
        v[0]=(short)f2b(f0.x); v[1]=(short)f2b(f0.y); v[2]=(short)f2b(f0.z); v[3]=(short)f2b(f0.w);
        v[4]=(short)f2b(f1.x); v[5]=(short)f2b(f1.y); v[6]=(short)f2b(f1.z); v[7]=(short)f2b(f1.w);
      } else {
        #pragma unroll
        for (int j=0;j<8;j++){
          int kk = k0 + oct*8 + j;
          float x = (kk < V_) ? src[j] : 0.f;
          v[j] = (short)f2b(x);
        }
      }
      *(short8*)(&At[row*40 + oct*8]) = v;
    }
    #pragma unroll
    for (int i=0;i<2;i++){
      int slot = tid + 256*i;
      int row = slot >> 2, oct = slot & 3;
      *(short8*)(&Bt[row*40 + oct*8]) = *(const short8*)(BT + (long)(n0+row)*KP2 + k0 + oct*8);
    }
    __syncthreads();
    short8 af[4], bf[4];
    #pragma unroll
    for (int i=0;i<4;i++){
      af[i] = *(const short8*)(&At[(wm + i*16 + l15)*40 + quad*8]);
      bf[i] = *(const short8*)(&Bt[(wn + i*16 + l15)*40 + quad*8]);
    }
    #pragma unroll
    for (int mi=0;mi<4;mi++)
      #pragma unroll
      for (int ni=0;ni<4;ni++)
        acc[mi][ni] = __builtin_amdgcn_mfma_f32_16x16x32_bf16(af[mi],bf[ni],acc[mi][ni],0,0,0);
    __syncthreads();
  }
  #pragma unroll
  for (int mi=0;mi<4;mi++)
    #pragma unroll
    for (int ni=0;ni<4;ni++){
      int n = n0 + wn + ni*16 + l15;
      #pragma unroll
      for (int r=0;r<4;r++){
        int m = m0 + wm + mi*16 + quad*4 + r;
        atomicAdd(&Mf32[(long)m*D_ + n], acc[mi][ni][r]);
      }
    }
}

// Lightweight grid barrier: per-phase monotonic counter, no cache flushes.
// h data goes through SYSTEM-scope (sc0 sc1) loads/stores, so no L2
// invalidation is needed; weights are read-only so their L2 copies are
// always valid. Correct on any block->XCD mapping.
__device__ __forceinline__ void gridbar(unsigned* barp, int tid){
  // drain this thread's outstanding stores before anyone arrives
  asm volatile("s_waitcnt vmcnt(0) lgkmcnt(0)" ::: "memory");
  __syncthreads();
  if (tid == 0){
    __hip_atomic_fetch_add(barp, 1u, __ATOMIC_RELAXED, __HIP_MEMORY_SCOPE_AGENT);
    while (__hip_atomic_load(barp, __ATOMIC_RELAXED, __HIP_MEMORY_SCOPE_AGENT) < (unsigned)NBLK)
      __builtin_amdgcn_s_sleep(2);
  }
  asm volatile("" ::: "memory");
  __syncthreads();
}

// One LSTM layer-phase: gates(32 x 16j x 4gates) = ha@WA^T + hb@WB^T + bias.
// h loads/stores are SYSTEM scope (coherent via IC); weights plain (L2-hot).
// All h words for the phase are burst-loaded into regs up front.
__device__ __forceinline__ void lstm_phase(
    const unsigned short* __restrict__ ha, const unsigned short* __restrict__ WA,
    const unsigned short* __restrict__ hb, const unsigned short* __restrict__ WB,
    const float* __restrict__ bias, float* __restrict__ creg,
    unsigned short* __restrict__ hout, short* smem,
    int br0, int j0, int tid)
{
  short* Aa = smem;                      // [32][72]
  short* Ab = smem + 32*72;              // [32][72]
  short* Ba = smem + 2*32*72;            // [64][72]
  short* Bb = smem + 2*32*72 + 64*72;    // [64][72]
  int lane = tid & 63, wave = tid >> 6;
  int l15 = lane & 15, quad = lane >> 4;
  int row = tid >> 3, oct = tid & 7;     // staging slot: 32 rows x 8 octs
  bool fA = (ha != nullptr), fB = (hb != nullptr);
  floatx4 acc[2];
  #pragma unroll
  for (int i=0;i<2;i++){ floatx4 z = {0.f,0.f,0.f,0.f}; acc[i] = z; }

  // burst-load all h words for this phase (IC latency paid once)
  unsigned pa[8][4], pb[8][4];
  const unsigned* hau = (const unsigned*)ha;
  const unsigned* hbu = (const unsigned*)hb;
  long abase = (long)(br0+row)*256 + oct*4;
  if (fA){
    #pragma unroll
    for (int it=0; it<8; ++it)
      #pragma unroll
      for (int s=0; s<4; ++s)
        pa[it][s] = __hip_atomic_load(hau + abase + it*32 + s,
                                      __ATOMIC_RELAXED, __HIP_MEMORY_SCOPE_SYSTEM);
  }
  if (fB){
    #pragma unroll
    for (int it=0; it<8; ++it)
      #pragma unroll
      for (int s=0; s<4; ++s)
        pb[it][s] = __hip_atomic_load(hbu + abase + it*32 + s,
                                      __ATOMIC_RELAXED, __HIP_MEMORY_SCOPE_SYSTEM);
  }

  #pragma unroll
  for (int it = 0; it < 8; ++it){
    int k0 = it*64;
    if (fA){
      #pragma unroll
      for (int s=0; s<4; ++s) *(unsigned*)(&Aa[row*72 + oct*8 + s*2]) = pa[it][s];
    }
    if (fB){
      #pragma unroll
      for (int s=0; s<4; ++s) *(unsigned*)(&Ab[row*72 + oct*8 + s*2]) = pb[it][s];
    }
    #pragma unroll
    for (int i=0;i<2;i++){
      int slot = tid + 256*i;                     // 512 slots: 64 rows x 8 octs
      int wrow = slot >> 3, woct = slot & 7;
      int g = (wrow>>4)*512 + j0 + (wrow&15);
      if (fA) *(short8*)(&Ba[wrow*72+woct*8]) = *(const short8*)(WA + (long)g*512 + k0 + woct*8);
      if (fB) *(short8*)(&Bb[wrow*72+woct*8]) = *(const short8*)(WB + (long)g*512 + k0 + woct*8);
    }
    __syncthreads();
    #pragma unroll
    for (int kk=0; kk<2; kk++){
      if (fA){
        short8 b = *(const short8*)(&Ba[(wave*16 + l15)*72 + kk*32 + quad*8]);
        #pragma unroll
        for (int mt=0; mt<2; mt++){
          short8 a = *(const short8*)(&Aa[(mt*16 + l15)*72 + kk*32 + quad*8]);
          acc[mt] = __builtin_amdgcn_mfma_f32_16x16x32_bf16(a,b,acc[mt],0,0,0);
        }
      }
      if (fB){
        short8 b = *(const short8*)(&Bb[(wave*16 + l15)*72 + kk*32 + quad*8]);
        #pragma unroll
        for (int mt=0; mt<2; mt++){
          short8 a = *(const short8*)(&Ab[(mt*16 + l15)*72 + kk*32 + quad*8]);
          acc[mt] = __builtin_amdgcn_mfma_f32_16x16x32_bf16(a,b,acc[mt],0,0,0);
        }
      }
    }
    __syncthreads();
  }
  // exchange gates through LDS: ex[gate][b_local][jj]
  float* ex = (float*)smem;    // 4*32*16 floats = 8 KB
  #pragma unroll
  for (int mt=0; mt<2; mt++)
    #pragma unroll
    for (int r=0;r<4;r++)
      ex[wave*512 + (mt*16 + quad*4 + r)*16 + l15] = acc[mt][r];
  __syncthreads();
  // pointwise: each thread owns 2 adjacent j for one b (stable across phases)
  {
    int bl = tid >> 3, jj = (tid & 7)*2;
    int b = br0 + bl, j = j0 + jj;
    float h2[2];
    #pragma unroll
    for (int q=0; q<2; q++){
      float gi = ex[0*512 + bl*16 + jj+q] + bias[j+q];
      float gf = ex[1*512 + bl*16 + jj+q] + bias[512+j+q];
      float gg = ex[2*512 + bl*16 + jj+q] + bias[1024+j+q];
      float go = ex[3*512 + bl*16 + jj+q] + bias[1536+j+q];
      float ig = sigm(gi), fg = sigm(gf), gt = tanhf(gg), og = sigm(go);
      float cn = fg*creg[q] + ig*gt;
      creg[q] = cn;
      h2[q] = og*tanhf(cn);
    }
    unsigned pack = (unsigned)f2b(h2[0]) | ((unsigned)f2b(h2[1]) << 16);
    __hip_atomic_store((unsigned*)(hout + (long)b*512 + j), pack,
                       __ATOMIC_RELAXED, __HIP_MEMORY_SCOPE_SYSTEM);
  }
}

// Persistent kernel: all T_=20 steps x 2 layers, custom barrier between phases.
__global__ __launch_bounds__(256) void k_lstm_all(
    const unsigned short* __restrict__ Mfold, const unsigned short* __restrict__ Whh0,
    const unsigned short* __restrict__ Wih1, const unsigned short* __restrict__ Whh1,
    const float* __restrict__ biasA0, const float* __restrict__ bfold,
    const float* __restrict__ bias1,
    unsigned short* __restrict__ h0b0, unsigned short* __restrict__ h0b1,
    unsigned short* __restrict__ Hs, unsigned* __restrict__ bar)
{
  __shared__ short smem[13824];          // 27648 B
  int tid = threadIdx.x;
  int jg = blockIdx.x & 31, bs = blockIdx.x >> 5;
  int br0 = bs*32, j0 = jg*16;
  float cr0[2] = {0.f, 0.f};
  float cr1[2] = {0.f, 0.f};
  unsigned short* hc = h0b0;             // current h0 (holds converted input at t=0)
  unsigned short* hn = h0b1;
  int phase = 0;
  for (int t = 0; t < T_; t++){
    const unsigned short* h1p = (t==0) ? nullptr : (Hs + (size_t)(t-1)*BD);
    lstm_phase(h1p, Mfold, hc, Whh0, (t==0)?biasA0:bfold, cr0, hn, smem, br0, j0, tid);
    gridbar(bar + phase, tid); phase++;
    lstm_phase(hn, Wih1, h1p, Whh1, bias1, cr1, Hs + (size_t)t*BD, smem, br0, j0, tid);
    gridbar(bar + phase, tid); phase++;
    unsigned short* tmp = hc; hc = hn; hn = tmp;
  }
}

// Out = Hs (2560x512 bf16) @ Wenc_b^T (+b_enc) -> fp32 (2560x10000)
__global__ __launch_bounds__(256) void k_out_gemm(
    const unsigned short* __restrict__ Ah,
    const unsigned short* __restrict__ Bw,
    const float* __restrict__ b_enc, float* __restrict__ out)
{
  __shared__ short At[128*40];
  __shared__ short Bt[128*40];
  int tid = threadIdx.x;
  int bm = blockIdx.x % 20, bn = blockIdx.x / 20;
  int m0 = bm*128, n0 = bn*128;
  int lane = tid&63, wave = tid>>6, l15 = lane&15, quad = lane>>4;
  int wm = (wave>>1)*64, wn = (wave&1)*64;
  floatx4 acc[4][4];
  #pragma unroll
  for (int i=0;i<4;i++)
    #pragma unroll
    for(int j=0;j<4;j++){ floatx4 z = {0.f,0.f,0.f,0.f}; acc[i][j] = z; }
  for (int k0=0;k0<512;k0+=32){
    #pragma unroll
    for (int i=0;i<2;i++){
      int cc = tid + 256*i; int row = cc>>2; int ko=(cc&3)*8;
      *(short8*)(&At[row*40+ko]) = *(const short8*)(Ah + (long)(m0+row)*512 + k0+ko);
      *(short8*)(&Bt[row*40+ko]) = *(const short8*)(Bw + (long)(n0+row)*512 + k0+ko);
    }
    __syncthreads();
    short8 af[4], bf[4];
    #pragma unroll
    for (int i=0;i<4;i++){
      af[i] = *(const short8*)(&At[(wm + i*16 + l15)*40 + quad*8]);
      bf[i] = *(const short8*)(&Bt[(wn + i*16 + l15)*40 + quad*8]);
    }
    #pragma unroll
    for (int mi=0;mi<4;mi++)
      #pragma unroll
      for (int ni=0;ni<4;ni++)
        acc[mi][ni] = __builtin_amdgcn_mfma_f32_16x16x32_bf16(af[mi],bf[ni],acc[mi][ni],0,0,0);
    __syncthreads();
  }
  #pragma unroll
  for (int mi=0;mi<4;mi++)
    #pragma unroll
    for (int ni=0;ni<4;ni++){
      int n = n0 + wn + ni*16 + l15;
      if (n < V_){
        float be = b_enc[n];
        #pragma unroll
        for (int r=0;r<4;r++){
          int m = m0 + wm + mi*16 + quad*4 + r;
          out[(long)m*V_ + n] = acc[mi][ni][r] + be;
        }
      }
    }
}

extern "C" void kernel_launch(void* const* d_in, const int* in_sizes, int n_in,
                              void* d_out, int out_size, void* d_ws, size_t ws_size,
                              hipStream_t stream){
  const float* input_ = (const float*)d_in[0];
  const float* W_ih0  = (const float*)d_in[1];
  const float* W_hh0  = (const float*)d_in[2];
  const float* b_ih0  = (const float*)d_in[3];
  const float* b_hh0  = (const float*)d_in[4];
  const float* W_ih1  = (const float*)d_in[5];
  const float* W_hh1  = (const float*)d_in[6];
  const float* b_ih1  = (const float*)d_in[7];
  const float* b_hh1  = (const float*)d_in[8];
  const float* W_enc  = (const float*)d_in[9];
  const float* b_enc  = (const float*)d_in[10];
  float* out = (float*)d_out;

  char* ws = (char*)d_ws;
  size_t off = 0;
  auto alloc = [&](size_t bytes){ void* p = ws + off; off += (bytes + 255) & ~255ull; return p; };
  unsigned short* Wenc_b  = (unsigned short*)alloc((size_t)VPAD*512*2);
  unsigned short* WencT_b = (unsigned short*)alloc((size_t)512*KP2*2);
  float*          Mf32    = (float*)alloc((size_t)G4*512*4);
  unsigned short* Mfold_b = (unsigned short*)alloc((size_t)G4*512*2);
  unsigned short* Whh0_b  = (unsigned short*)alloc((size_t)G4*512*2);
  unsigned short* Wih1_b  = (unsigned short*)alloc((size_t)G4*512*2);
  unsigned short* Whh1_b  = (unsigned short*)alloc((size_t)G4*512*2);
  unsigned short* Hs_b    = (unsigned short*)alloc((size_t)T_*BD*2);
  unsigned short* h0b0    = (unsigned short*)alloc((size_t)BD*2);
  unsigned short* h0b1    = (unsigned short*)alloc((size_t)BD*2);
  float* biasA0 = (float*)alloc(2048*4);
  float* bfold  = (float*)alloc(2048*4);
  float* bias1  = (float*)alloc(2048*4);
  unsigned* bar = (unsigned*)alloc(64*4);

  k_trans<<<dim3(KP2/64, 512/64), 256, 0, stream>>>(W_enc, Wenc_b, WencT_b);
  k_convert<<<(G4*512+255)/256, 256, 0, stream>>>(W_hh0, Whh0_b, G4*512);
  k_convert<<<(G4*512+255)/256, 256, 0, stream>>>(W_ih1, Wih1_b, G4*512);
  k_convert<<<(G4*512+255)/256, 256, 0, stream>>>(W_hh1, Whh1_b, G4*512);
  k_convert<<<(BD+255)/256, 256, 0, stream>>>(input_, h0b0, BD);
  k_zero<<<(G4*512+255)/256, 256, 0, stream>>>(Mf32, G4*512);
  k_zero<<<1, 256, 0, stream>>>((float*)bar, 64);
  k_addvec<<<8, 256, 0, stream>>>(b_ih1, b_hh1, bias1, 2048);
  k_bias_fold<<<2048, 256, 0, stream>>>(W_ih0, b_enc, b_ih0, b_hh0, biasA0, bfold);
  k_fold_gemm<<<512, 256, 0, stream>>>(W_ih0, WencT_b, Mf32);
  k_convert<<<(G4*512+255)/256, 256, 0, stream>>>(Mf32, Mfold_b, G4*512);

  {
    const unsigned short* a0 = Mfold_b; const unsigned short* a1 = Whh0_b;
    const unsigned short* a2 = Wih1_b; const unsigned short* a3 = Whh1_b;
    const float* a4 = biasA0; const float* a5 = bfold; const float* a6 = bias1;
    unsigned short* a7 = h0b0; unsigned short* a8 = h0b1; unsigned short* a9 = Hs_b;
    unsigned* a10 = bar;
    void* args[] = {&a0,&a1,&a2,&a3,&a4,&a5,&a6,&a7,&a8,&a9,&a10};
    hipLaunchCooperativeKernel((void*)k_lstm_all, dim3(NBLK), dim3(256), args, 0u, stream);
  }

  k_out_gemm<<<20*79, 256, 0, stream>>>(Hs_b, Wenc_b, b_enc, out);
}

// Round 3
// 666.229 us; speedup vs baseline: 2.2416x; 1.5275x over previous
//
#include <hip/hip_runtime.h>

typedef __attribute__((ext_vector_type(8))) short short8;
typedef __attribute__((ext_vector_type(4))) short short4v;
typedef __attribute__((ext_vector_type(4))) float floatx4;

#define B_   128
#define D_   512
#define V_   10000
#define T_   20
#define G4   2048
#define VPAD 10112
#define KP2  10240
#define BD   (B_*D_)

__device__ __forceinline__ unsigned short f2b(float x){
  union { float f; unsigned u; } c; c.f = x;
  unsigned u = c.u;
  unsigned r = (u + 0x7fffu + ((u>>16)&1u)) >> 16;
  return (unsigned short)r;
}
__device__ __forceinline__ float sigm(float x){ return 1.0f/(1.0f+__expf(-x)); }

__global__ void k_convert(const float* __restrict__ src, unsigned short* __restrict__ dst, int n){
  int i = blockIdx.x*256 + threadIdx.x;
  if (i < n) dst[i] = f2b(src[i]);
}

// Merged prep: 3 weight converts, input convert, bias1 add, Mf32 zero, bar zero.
__global__ void k_prep(const float* __restrict__ Whh0, const float* __restrict__ Wih1,
                       const float* __restrict__ Whh1, const float* __restrict__ input_,
                       const float* __restrict__ b_ih1, const float* __restrict__ b_hh1,
                       unsigned short* __restrict__ Whh0_b, unsigned short* __restrict__ Wih1_b,
                       unsigned short* __restrict__ Whh1_b, unsigned short* __restrict__ h0b0,
                       float* __restrict__ bias1, float* __restrict__ Mf32,
                       unsigned* __restrict__ bar){
  int i = blockIdx.x*256 + threadIdx.x;
  const int NW = G4*512;
  if (i < NW){
    Whh0_b[i] = f2b(Whh0[i]);
    Wih1_b[i] = f2b(Wih1[i]);
    Whh1_b[i] = f2b(Whh1[i]);
    Mf32[i] = 0.f;
  }
  if (i < BD) h0b0[i] = f2b(input_[i]);
  if (i < 2048) bias1[i] = b_ih1[i] + b_hh1[i];
  if (i < 40*8*16) bar[i] = 0u;
}

// Transpose+convert W_enc (10000x512 fp32) into:
//   Wenc_b  [VPAD][512]  bf16 (row-major, for out_gemm; rows >=10000 zero)
//   WencT_b [512][KP2]   bf16 (K-major, for fold_gemm; cols >=10000 zero)
__global__ __launch_bounds__(256) void k_trans(const float* __restrict__ Wenc,
    unsigned short* __restrict__ Wenc_b, unsigned short* __restrict__ WencT){
  __shared__ short T[64*72];
  int tid = threadIdx.x;
  int v0 = blockIdx.x * 64;
  int d0 = blockIdx.y * 64;
  #pragma unroll
  for (int i=0;i<4;i++){
    int s = tid + 256*i;
    int row = s >> 4, fq = s & 15;
    int v = v0 + row, d = d0 + fq*4;
    float4 f = {0.f,0.f,0.f,0.f};
    if (v < V_) f = *(const float4*)(Wenc + (long)v*D_ + d);
    short4v h; h[0]=(short)f2b(f.x); h[1]=(short)f2b(f.y); h[2]=(short)f2b(f.z); h[3]=(short)f2b(f.w);
    *(short4v*)(&T[row*72 + fq*4]) = h;
    if (v < VPAD) *(short4v*)(Wenc_b + (long)v*D_ + d) = h;
  }
  __syncthreads();
  #pragma unroll
  for (int i=0;i<2;i++){
    int s = tid + 256*i;
    int drow = s >> 3, oct = s & 7;
    short8 v8;
    #pragma unroll
    for (int j=0;j<8;j++) v8[j] = T[(oct*8+j)*72 + drow];
    *(short8*)(WencT + (long)(d0+drow)*KP2 + v0 + oct*8) = v8;
  }
}

// bfold[g] = b_ih0[g]+b_hh0[g] + sum_v W_ih0[g][v]*b_enc[v]; biasA0 = b_ih0+b_hh0
__global__ void k_bias_fold(const float* __restrict__ Wih0, const float* __restrict__ b_enc,
                            const float* __restrict__ b_ih0, const float* __restrict__ b_hh0,
                            float* __restrict__ biasA0, float* __restrict__ bfold){
  __shared__ float red[256];
  int g = blockIdx.x;
  const float* row = Wih0 + (long)g*V_;
  float s = 0.f;
  for (int v = threadIdx.x; v < V_; v += 256) s += row[v]*b_enc[v];
  red[threadIdx.x] = s; __syncthreads();
  for (int w = 128; w >= 1; w >>= 1){
    if (threadIdx.x < w) red[threadIdx.x] += red[threadIdx.x+w];
    __syncthreads();
  }
  if (threadIdx.x == 0){
    float ba = b_ih0[g] + b_hh0[g];
    biasA0[g] = ba;
    bfold[g]  = ba + red[0];
  }
}

// Mf32 (2048x512 fp32, atomically accumulated) += W_ih0 (fp32, inline bf16) @ WencT^T
// Grid: 4 ksplits x 16 m-blocks x 4 n-blocks = 256 blocks; 128x128 tile, K=2560 each.
__global__ __launch_bounds__(256) void k_fold_gemm(const float* __restrict__ A,
                 const unsigned short* __restrict__ BT, float* __restrict__ Mf32){
  __shared__ short At[128*40];
  __shared__ short Bt[128*40];
  int tid = threadIdx.x;
  int b = blockIdx.x;
  int ks = b >> 6, mn = b & 63;
  int bm = mn >> 2, bn = mn & 3;
  int m0 = bm*128, n0 = bn*128, kb = ks*2560;
  int lane = tid&63, wave = tid>>6, l15 = lane&15, quad = lane>>4;
  int wm = (wave>>1)*64, wn = (wave&1)*64;
  floatx4 acc[4][4];
  #pragma unroll
  for (int i=0;i<4;i++)
    #pragma unroll
    for(int j=0;j<4;j++){ floatx4 z = {0.f,0.f,0.f,0.f}; acc[i][j] = z; }
  for (int it = 0; it < 80; it++){
    int k0 = kb + it*32;
    #pragma unroll
    for (int i=0;i<2;i++){
      int slot = tid + 256*i;
      int row = slot >> 2, oct = slot & 3;
      const float* src = A + (long)(m0+row)*V_ + k0 + oct*8;
      short8 v;
      if (k0 + 32 <= V_){
        float4 f0 = *(const float4*)src;
        float4 f1 = *(const float4*)(src+4);
        v[0]=(short)f2b(f0.x); v[1]=(short)f2b(f0.y); v[2]=(short)f2b(f0.z); v[3]=(short)f2b(f0.w);
        v[4]=(short)f2b(f1.x); v[5]=(short)f2b(f1.y); v[6]=(short)f2b(f1.z); v[7]=(short)f2b(f1.w);
      } else {
        #pragma unroll
        for (int j=0;j<8;j++){
          int kk = k0 + oct*8 + j;
          float x = (kk < V_) ? src[j] : 0.f;
          v[j] = (short)f2b(x);
        }
      }
      *(short8*)(&At[row*40 + oct*8]) = v;
    }
    #pragma unroll
    for (int i=0;i<2;i++){
      int slot = tid + 256*i;
      int row = slot >> 2, oct = slot & 3;
      *(short8*)(&Bt[row*40 + oct*8]) = *(const short8*)(BT + (long)(n0+row)*KP2 + k0 + oct*8);
    }
    __syncthreads();
    short8 af[4], bf[4];
    #pragma unroll
    for (int i=0;i<4;i++){
      af[i] = *(const short8*)(&At[(wm + i*16 + l15)*40 + quad*8]);
      bf[i] = *(const short8*)(&Bt[(wn + i*16 + l15)*40 + quad*8]);
    }
    #pragma unroll
    for (int mi=0;mi<4;mi++)
      #pragma unroll
      for (int ni=0;ni<4;ni++)
        acc[mi][ni] = __builtin_amdgcn_mfma_f32_16x16x32_bf16(af[mi],bf[ni],acc[mi][ni],0,0,0);
    __syncthreads();
  }
  #pragma unroll
  for (int mi=0;mi<4;mi++)
    #pragma unroll
    for (int ni=0;ni<4;ni++){
      int n = n0 + wn + ni*16 + l15;
      #pragma unroll
      for (int r=0;r<4;r++){
        int m = m0 + wm + mi*16 + quad*4 + r;
        atomicAdd(&Mf32[(long)m*D_ + n], acc[mi][ni][r]);
      }
    }
}

// ---------- persistent LSTM ----------
// 256 blocks = 2 layers x (32 jg x 4 bs). Weights live in registers (32 B-frags
// per wave). LDS holds only the two h input tiles [32][520] (padded) + gate
// exchange. Sync: per-phase arrival counters spread over 8 cachelines.

#define LSTRIDE 520
#define LDS_TILE (32*LSTRIDE)

__device__ __forceinline__ void wait_phase(const unsigned* __restrict__ bar, int p, int tid){
  if (tid < 64){
    const unsigned* cp = bar + (p*8 + (tid&7))*16;
    bool ok;
    do {
      unsigned v = 16u;
      if (tid < 8) v = __hip_atomic_load(cp, __ATOMIC_RELAXED, __HIP_MEMORY_SCOPE_AGENT);
      ok = __all(v >= 16u) != 0;
      if (!ok) __builtin_amdgcn_s_sleep(1);
    } while (!ok);
  }
  __syncthreads();
  asm volatile("" ::: "memory");
}

__device__ __forceinline__ void arrive_phase(unsigned* __restrict__ bar, int p, int slot, int tid){
  asm volatile("s_waitcnt vmcnt(0) lgkmcnt(0)" ::: "memory");
  __syncthreads();
  if (tid == 0)
    __hip_atomic_fetch_add(bar + (p*8 + slot)*16, 1u, __ATOMIC_RELAXED, __HIP_MEMORY_SCOPE_AGENT);
}

// Stage one 32x512 bf16 h tile (rows br0..br0+31) into LDS (row stride 520).
// System-scope 8B loads (coherent via IC), issued as a burst.
__device__ __forceinline__ void stage_tile(const unsigned short* __restrict__ src,
                                           short* __restrict__ dst, int br0, int tid){
  unsigned long long u[16];
  #pragma unroll
  for (int i=0;i<8;i++){
    int c = tid + 256*i;          // 2048 chunks: 32 rows x 64 x 16B
    int r = c >> 6, o = c & 63;
    const unsigned long long* p = (const unsigned long long*)(src + (long)(br0 + r)*512 + o*8);
    u[2*i]   = __hip_atomic_load(p,   __ATOMIC_RELAXED, __HIP_MEMORY_SCOPE_SYSTEM);
    u[2*i+1] = __hip_atomic_load(p+1, __ATOMIC_RELAXED, __HIP_MEMORY_SCOPE_SYSTEM);
  }
  #pragma unroll
  for (int i=0;i<8;i++){
    int c = tid + 256*i;
    int r = c >> 6, o = c & 63;
    unsigned long long* q = (unsigned long long*)(dst + r*LSTRIDE + o*8);
    q[0] = u[2*i]; q[1] = u[2*i+1];
  }
}

__global__ __launch_bounds__(256, 1) void k_lstm_all(
    const unsigned short* __restrict__ Mfold, const unsigned short* __restrict__ Whh0,
    const unsigned short* __restrict__ Wih1, const unsigned short* __restrict__ Whh1,
    const float* __restrict__ biasA0, const float* __restrict__ bfold,
    const float* __restrict__ bias1,
    unsigned short* __restrict__ h0b0, unsigned short* __restrict__ h0b1,
    unsigned short* __restrict__ Hs, unsigned* __restrict__ bar)
{
  __shared__ short smem[2*LDS_TILE];     // 66,560 B: tileA | tileB (ex reuses tileA)
  short* ldsA = smem;
  short* ldsB = smem + LDS_TILE;

  int tid = threadIdx.x;
  int L   = blockIdx.x >> 7;             // 0 or 1
  int idx = blockIdx.x & 127;
  int jg = idx & 31, bs = idx >> 5;
  int br0 = bs*32, j0 = jg*16;
  int slot = idx & 7;
  int lane = tid & 63, wave = tid >> 6;
  int l15 = lane & 15, quad = lane >> 4;

  // ---- preload weight B-fragments into registers (once) ----
  const unsigned short* WA = (L==0) ? Mfold : Wih1;
  const unsigned short* WB = (L==0) ? Whh0  : Whh1;
  int gRow = wave*512 + j0 + l15;        // wave = gate
  short8 bfa[16], bfb[16];
  #pragma unroll
  for (int ks=0; ks<16; ks++){
    bfa[ks] = *(const short8*)(WA + (long)gRow*512 + ks*32 + quad*8);
    bfb[ks] = *(const short8*)(WB + (long)gRow*512 + ks*32 + quad*8);
  }

  // ---- preload biases for this thread's (bl, j-pair) ----
  int bl = tid >> 3, jjp = (tid & 7)*2;
  int jglob = j0 + jjp;
  float b0g[4][2], bNg[4][2];
  #pragma unroll
  for (int gg=0; gg<4; gg++)
    #pragma unroll
    for (int q=0; q<2; q++){
      if (L==0){
        b0g[gg][q] = biasA0[gg*512 + jglob + q];
        bNg[gg][q] = bfold [gg*512 + jglob + q];
      } else {
        b0g[gg][q] = bias1 [gg*512 + jglob + q];
        bNg[gg][q] = b0g[gg][q];
      }
    }

  float creg[2] = {0.f, 0.f};
  unsigned short* bufs[2] = {h0b0, h0b1};

  for (int t = 0; t < T_; t++){
    const unsigned short *haP, *hbP; unsigned short* hoP;
    bool hasA, hasB; int p_own, p_oth, p_arr;
    if (L == 0){
      haP = (t>0) ? (Hs + (size_t)(t-1)*BD) : nullptr;   // h1[t-1] via Mfold
      hbP = bufs[t&1];                                    // h0[t-1]
      hoP = bufs[(t+1)&1];
      hasA = (t>0); hasB = true;
      p_own = 2*(t-1); p_oth = 2*(t-1)+1; p_arr = 2*t;
    } else {
      haP = bufs[(t+1)&1];                                // h0[t]
      hbP = (t>0) ? (Hs + (size_t)(t-1)*BD) : nullptr;    // h1[t-1]
      hoP = Hs + (size_t)t*BD;
      hasA = true; hasB = (t>0);
      p_own = 2*(t-1)+1; p_oth = 2*t; p_arr = 2*t+1;
    }

    if (hasB){
      if (t > 0) wait_phase(bar, p_own, tid);   // own layer's prev phase (fast)
      stage_tile(hbP, ldsB, br0, tid);
    }
    if (hasA){
      wait_phase(bar, p_oth, tid);              // other layer's phase (critical)
      stage_tile(haP, ldsA, br0, tid);
    }
    __syncthreads();

    floatx4 acc[2];
    #pragma unroll
    for (int i=0;i<2;i++){ floatx4 z = {0.f,0.f,0.f,0.f}; acc[i] = z; }
    if (hasA){
      #pragma unroll
      for (int ks=0; ks<16; ks++)
        #pragma unroll
        for (int mt=0; mt<2; mt++){
          short8 a = *(const short8*)(ldsA + (mt*16 + l15)*LSTRIDE + ks*32 + quad*8);
          acc[mt] = __builtin_amdgcn_mfma_f32_16x16x32_bf16(a, bfa[ks], acc[mt], 0,0,0);
        }
    }
    if (hasB){
      #pragma unroll
      for (int ks=0; ks<16; ks++)
        #pragma unroll
        for (int mt=0; mt<2; mt++){
          short8 a = *(const short8*)(ldsB + (mt*16 + l15)*LSTRIDE + ks*32 + quad*8);
          acc[mt] = __builtin_amdgcn_mfma_f32_16x16x32_bf16(a, bfb[ks], acc[mt], 0,0,0);
        }
    }
    __syncthreads();

    // gate exchange: ex[gate][bl][jj]  (reuses tileA region)
    float* ex = (float*)smem;
    #pragma unroll
    for (int mt=0; mt<2; mt++)
      #pragma unroll
      for (int r=0; r<4; r++)
        ex[wave*512 + (mt*16 + quad*4 + r)*16 + l15] = acc[mt][r];
    __syncthreads();

    // pointwise: this thread owns (bl, jjp..jjp+1); c in registers
    {
      float h2[2];
      #pragma unroll
      for (int q=0; q<2; q++){
        float bi = (t==0) ? b0g[0][q] : bNg[0][q];
        float bf_ = (t==0) ? b0g[1][q] : bNg[1][q];
        float bg = (t==0) ? b0g[2][q] : bNg[2][q];
        float bo = (t==0) ? b0g[3][q] : bNg[3][q];
        float gi = ex[0*512 + bl*16 + jjp+q] + bi;
        float gf = ex[1*512 + bl*16 + jjp+q] + bf_;
        float gg = ex[2*512 + bl*16 + jjp+q] + bg;
        float go = ex[3*512 + bl*16 + jjp+q] + bo;
        float ig = sigm(gi), fg = sigm(gf), gt = tanhf(gg), og = sigm(go);
        float cn = fg*creg[q] + ig*gt;
        creg[q] = cn;
        h2[q] = og*tanhf(cn);
      }
      unsigned pack = (unsigned)f2b(h2[0]) | ((unsigned)f2b(h2[1]) << 16);
      __hip_atomic_store((unsigned*)(hoP + (long)(br0 + bl)*512 + jglob), pack,
                         __ATOMIC_RELAXED, __HIP_MEMORY_SCOPE_SYSTEM);
    }
    arrive_phase(bar, p_arr, slot, tid);
  }
}

// Out = Hs (2560x512 bf16) @ Wenc_b^T (+b_enc) -> fp32 (2560x10000)
__global__ __launch_bounds__(256) void k_out_gemm(
    const unsigned short* __restrict__ Ah,
    const unsigned short* __restrict__ Bw,
    const float* __restrict__ b_enc, float* __restrict__ out)
{
  __shared__ short At[128*40];
  __shared__ short Bt[128*40];
  int tid = threadIdx.x;
  int bm = blockIdx.x % 20, bn = blockIdx.x / 20;
  int m0 = bm*128, n0 = bn*128;
  int lane = tid&63, wave = tid>>6, l15 = lane&15, quad = lane>>4;
  int wm = (wave>>1)*64, wn = (wave&1)*64;
  floatx4 acc[4][4];
  #pragma unroll
  for (int i=0;i<4;i++)
    #pragma unroll
    for(int j=0;j<4;j++){ floatx4 z = {0.f,0.f,0.f,0.f}; acc[i][j] = z; }
  for (int k0=0;k0<512;k0+=32){
    #pragma unroll
    for (int i=0;i<2;i++){
      int cc = tid + 256*i; int row = cc>>2; int ko=(cc&3)*8;
      *(short8*)(&At[row*40+ko]) = *(const short8*)(Ah + (long)(m0+row)*512 + k0+ko);
      *(short8*)(&Bt[row*40+ko]) = *(const short8*)(Bw + (long)(n0+row)*512 + k0+ko);
    }
    __syncthreads();
    short8 af[4], bf[4];
    #pragma unroll
    for (int i=0;i<4;i++){
      af[i] = *(const short8*)(&At[(wm + i*16 + l15)*40 + quad*8]);
      bf[i] = *(const short8*)(&Bt[(wn + i*16 + l15)*40 + quad*8]);
    }
    #pragma unroll
    for (int mi=0;mi<4;mi++)
      #pragma unroll
      for (int ni=0;ni<4;ni++)
        acc[mi][ni] = __builtin_amdgcn_mfma_f32_16x16x32_bf16(af[mi],bf[ni],acc[mi][ni],0,0,0);
    __syncthreads();
  }
  #pragma unroll
  for (int mi=0;mi<4;mi++)
    #pragma unroll
    for (int ni=0;ni<4;ni++){
      int n = n0 + wn + ni*16 + l15;
      if (n < V_){
        float be = b_enc[n];
        #pragma unroll
        for (int r=0;r<4;r++){
          int m = m0 + wm + mi*16 + quad*4 + r;
          out[(long)m*V_ + n] = acc[mi][ni][r] + be;
        }
      }
    }
}

extern "C" void kernel_launch(void* const* d_in, const int* in_sizes, int n_in,
                              void* d_out, int out_size, void* d_ws, size_t ws_size,
                              hipStream_t stream){
  const float* input_ = (const float*)d_in[0];
  const float* W_ih0  = (const float*)d_in[1];
  const float* W_hh0  = (const float*)d_in[2];
  const float* b_ih0  = (const float*)d_in[3];
  const float* b_hh0  = (const float*)d_in[4];
  const float* W_ih1  = (const float*)d_in[5];
  const float* W_hh1  = (const float*)d_in[6];
  const float* b_ih1  = (const float*)d_in[7];
  const float* b_hh1  = (const float*)d_in[8];
  const float* W_enc  = (const float*)d_in[9];
  const float* b_enc  = (const float*)d_in[10];
  float* out = (float*)d_out;

  char* ws = (char*)d_ws;
  size_t off = 0;
  auto alloc = [&](size_t bytes){ void* p = ws + off; off += (bytes + 255) & ~255ull; return p; };
  unsigned short* Wenc_b  = (unsigned short*)alloc((size_t)VPAD*512*2);
  unsigned short* WencT_b = (unsigned short*)alloc((size_t)512*KP2*2);
  float*          Mf32    = (float*)alloc((size_t)G4*512*4);
  unsigned short* Mfold_b = (unsigned short*)alloc((size_t)G4*512*2);
  unsigned short* Whh0_b  = (unsigned short*)alloc((size_t)G4*512*2);
  unsigned short* Wih1_b  = (unsigned short*)alloc((size_t)G4*512*2);
  unsigned short* Whh1_b  = (unsigned short*)alloc((size_t)G4*512*2);
  unsigned short* Hs_b    = (unsigned short*)alloc((size_t)T_*BD*2);
  unsigned short* h0b0    = (unsigned short*)alloc((size_t)BD*2);
  unsigned short* h0b1    = (unsigned short*)alloc((size_t)BD*2);
  float* biasA0 = (float*)alloc(2048*4);
  float* bfold  = (float*)alloc(2048*4);
  float* bias1  = (float*)alloc(2048*4);
  unsigned* bar = (unsigned*)alloc((size_t)40*8*16*4);

  k_prep<<<4096, 256, 0, stream>>>(W_hh0, W_ih1, W_hh1, input_, b_ih1, b_hh1,
                                   Whh0_b, Wih1_b, Whh1_b, h0b0, bias1, Mf32, bar);
  k_trans<<<dim3(KP2/64, 512/64), 256, 0, stream>>>(W_enc, Wenc_b, WencT_b);
  k_bias_fold<<<2048, 256, 0, stream>>>(W_ih0, b_enc, b_ih0, b_hh0, biasA0, bfold);
  k_fold_gemm<<<256, 256, 0, stream>>>(W_ih0, WencT_b, Mf32);
  k_convert<<<(G4*512+255)/256, 256, 0, stream>>>(Mf32, Mfold_b, G4*512);

  {
    const unsigned short* a0 = Mfold_b; const unsigned short* a1 = Whh0_b;
    const unsigned short* a2 = Wih1_b; const unsigned short* a3 = Whh1_b;
    const float* a4 = biasA0; const float* a5 = bfold; const float* a6 = bias1;
    unsigned short* a7 = h0b0; unsigned short* a8 = h0b1; unsigned short* a9 = Hs_b;
    unsigned* a10 = bar;
    void* args[] = {&a0,&a1,&a2,&a3,&a4,&a5,&a6,&a7,&a8,&a9,&a10};
    hipLaunchCooperativeKernel((void*)k_lstm_all, dim3(256), dim3(256), args, 0u, stream);
  }

  k_out_gemm<<<20*79, 256, 0, stream>>>(Hs_b, Wenc_b, b_enc, out);
}

// Round 5
// 631.950 us; speedup vs baseline: 2.3632x; 1.0542x over previous
//
#include <hip/hip_runtime.h>

typedef __attribute__((ext_vector_type(8))) short short8;
typedef __attribute__((ext_vector_type(4))) short short4v;
typedef __attribute__((ext_vector_type(4))) float floatx4;

#define B_   128
#define D_   512
#define V_   10000
#define T_   20
#define G4   2048
#define VPAD 10112
#define KP2  10240
#define BD   (B_*D_)

__device__ __forceinline__ unsigned short f2b(float x){
  union { float f; unsigned u; } c; c.f = x;
  unsigned u = c.u;
  unsigned r = (u + 0x7fffu + ((u>>16)&1u)) >> 16;
  return (unsigned short)r;
}
__device__ __forceinline__ float sigm(float x){ return 1.0f/(1.0f+__expf(-x)); }

__global__ void k_convert(const float* __restrict__ src, unsigned short* __restrict__ dst, int n){
  int i = blockIdx.x*256 + threadIdx.x;
  if (i < n) dst[i] = f2b(src[i]);
}

// Merged prep: 3 weight converts, input convert, bias1 add, Mf32 zero, flags zero.
__global__ void k_prep(const float* __restrict__ Whh0, const float* __restrict__ Wih1,
                       const float* __restrict__ Whh1, const float* __restrict__ input_,
                       const float* __restrict__ b_ih1, const float* __restrict__ b_hh1,
                       unsigned short* __restrict__ Whh0_b, unsigned short* __restrict__ Wih1_b,
                       unsigned short* __restrict__ Whh1_b, unsigned short* __restrict__ h0b0,
                       float* __restrict__ bias1, float* __restrict__ Mf32,
                       unsigned* __restrict__ bar){
  int i = blockIdx.x*256 + threadIdx.x;
  const int NW = G4*512;
  if (i < NW){
    Whh0_b[i] = f2b(Whh0[i]);
    Wih1_b[i] = f2b(Wih1[i]);
    Whh1_b[i] = f2b(Whh1[i]);
    Mf32[i] = 0.f;
  }
  if (i < BD) h0b0[i] = f2b(input_[i]);
  if (i < 2048) bias1[i] = b_ih1[i] + b_hh1[i];
  if (i < 40*4*32) bar[i] = 0u;
}

// Transpose+convert W_enc (10000x512 fp32) into:
//   Wenc_b  [VPAD][512]  bf16 (row-major, for out_gemm; rows >=10000 zero)
//   WencT_b [512][KP2]   bf16 (K-major, for fold_gemm; cols >=10000 zero)
__global__ __launch_bounds__(256) void k_trans(const float* __restrict__ Wenc,
    unsigned short* __restrict__ Wenc_b, unsigned short* __restrict__ WencT){
  __shared__ short T[64*72];
  int tid = threadIdx.x;
  int v0 = blockIdx.x * 64;
  int d0 = blockIdx.y * 64;
  #pragma unroll
  for (int i=0;i<4;i++){
    int s = tid + 256*i;
    int row = s >> 4, fq = s & 15;
    int v = v0 + row, d = d0 + fq*4;
    float4 f = {0.f,0.f,0.f,0.f};
    if (v < V_) f = *(const float4*)(Wenc + (long)v*D_ + d);
    short4v h; h[0]=(short)f2b(f.x); h[1]=(short)f2b(f.y); h[2]=(short)f2b(f.z); h[3]=(short)f2b(f.w);
    *(short4v*)(&T[row*72 + fq*4]) = h;
    if (v < VPAD) *(short4v*)(Wenc_b + (long)v*D_ + d) = h;
  }
  __syncthreads();
  #pragma unroll
  for (int i=0;i<2;i++){
    int s = tid + 256*i;
    int drow = s >> 3, oct = s & 7;
    short8 v8;
    #pragma unroll
    for (int j=0;j<8;j++) v8[j] = T[(oct*8+j)*72 + drow];
    *(short8*)(WencT + (long)(d0+drow)*KP2 + v0 + oct*8) = v8;
  }
}

// bfold[g] = b_ih0[g]+b_hh0[g] + sum_v W_ih0[g][v]*b_enc[v]; biasA0 = b_ih0+b_hh0
__global__ void k_bias_fold(const float* __restrict__ Wih0, const float* __restrict__ b_enc,
                            const float* __restrict__ b_ih0, const float* __restrict__ b_hh0,
                            float* __restrict__ biasA0, float* __restrict__ bfold){
  __shared__ float red[256];
  int g = blockIdx.x;
  const float* row = Wih0 + (long)g*V_;
  float s = 0.f;
  for (int v = threadIdx.x; v < V_; v += 256) s += row[v]*b_enc[v];
  red[threadIdx.x] = s; __syncthreads();
  for (int w = 128; w >= 1; w >>= 1){
    if (threadIdx.x < w) red[threadIdx.x] += red[threadIdx.x+w];
    __syncthreads();
  }
  if (threadIdx.x == 0){
    float ba = b_ih0[g] + b_hh0[g];
    biasA0[g] = ba;
    bfold[g]  = ba + red[0];
  }
}

// Mf32 (2048x512 fp32, atomically accumulated) += W_ih0 (fp32, inline bf16) @ WencT^T
// 256 blocks; XCD-sibling swizzle: the 4 bn-siblings of one (bm,ks) A-panel share
// an XCD (b%8) so the fp32 A-panel is HBM-fetched once, L2-served 3x.
__global__ __launch_bounds__(256) void k_fold_gemm(const float* __restrict__ A,
                 const unsigned short* __restrict__ BT, float* __restrict__ Mf32){
  __shared__ short At[128*40];
  __shared__ short Bt[128*40];
  int tid = threadIdx.x;
  int b = blockIdx.x;
  int x = b & 7;
  int bn = (b >> 3) & 3;
  int idx = (b >> 5) * 8 + x;          // 0..63
  int bm = idx & 15, ks = idx >> 4;
  int m0 = bm*128, n0 = bn*128, kb = ks*2560;
  int lane = tid&63, wave = tid>>6, l15 = lane&15, quad = lane>>4;
  int wm = (wave>>1)*64, wn = (wave&1)*64;
  floatx4 acc[4][4];
  #pragma unroll
  for (int i=0;i<4;i++)
    #pragma unroll
    for(int j=0;j<4;j++){ floatx4 z = {0.f,0.f,0.f,0.f}; acc[i][j] = z; }
  for (int it = 0; it < 80; it++){
    int k0 = kb + it*32;
    #pragma unroll
    for (int i=0;i<2;i++){
      int slot = tid + 256*i;
      int row = slot >> 2, oct = slot & 3;
      const float* src = A + (long)(m0+row)*V_ + k0 + oct*8;
      short8 v;
      if (k0 + 32 <= V_){
        float4 f0 = *(const float4*)src;
        float4 f1 = *(const float4*)(src+4);
        v[0]=(short)f2b(f0.x); v[1]=(short)f2b(f0.y); v[2]=(short)f2b(f0.z); v[3]=(short)f2b(f0.w);
        v[4]=(short)f2b(f1.x); v[5]=(short)f2b(f1.y); v[6]=(short)f2b(f1.z); v[7]=(short)f2b(f1.w);
      } else {
        #pragma unroll
        for (int j=0;j<8;j++){
          int kk = k0 + oct*8 + j;
          float xx = (kk < V_) ? src[j] : 0.f;
          v[j] = (short)f2b(xx);
        }
      }
      *(short8*)(&At[row*40 + oct*8]) = v;
    }
    #pragma unroll
    for (int i=0;i<2;i++){
      int slot = tid + 256*i;
      int row = slot >> 2, oct = slot & 3;
      *(short8*)(&Bt[row*40 + oct*8]) = *(const short8*)(BT + (long)(n0+row)*KP2 + k0 + oct*8);
    }
    __syncthreads();
    short8 af[4], bf[4];
    #pragma unroll
    for (int i=0;i<4;i++){
      af[i] = *(const short8*)(&At[(wm + i*16 + l15)*40 + quad*8]);
      bf[i] = *(const short8*)(&Bt[(wn + i*16 + l15)*40 + quad*8]);
    }
    #pragma unroll
    for (int mi=0;mi<4;mi++)
      #pragma unroll
      for (int ni=0;ni<4;ni++)
        acc[mi][ni] = __builtin_amdgcn_mfma_f32_16x16x32_bf16(af[mi],bf[ni],acc[mi][ni],0,0,0);
    __syncthreads();
  }
  #pragma unroll
  for (int mi=0;mi<4;mi++)
    #pragma unroll
    for (int ni=0;ni<4;ni++){
      int n = n0 + wn + ni*16 + l15;
      #pragma unroll
      for (int r=0;r<4;r++){
        int m = m0 + wm + mi*16 + quad*4 + r;
        atomicAdd(&Mf32[(long)m*D_ + n], acc[mi][ni][r]);
      }
    }
}

// ---------- persistent LSTM ----------
// 256 blocks = 2 layers x (32 jg x 4 bs). Weights in registers. Sync: one flag
// word per producer block per phase, flags[p][bs][jg]; a consumer only needs
// the 32 same-bs producers. Producer: plain system store (no RMW). Consumer:
// wave0 lanes 0-31 poll 32 words (2 cachelines) + __all.

#define LSTRIDE 520
#define LDS_TILE (32*LSTRIDE)

__device__ __forceinline__ void wait_flags(const unsigned* __restrict__ fl, int tid){
  if (tid < 64){
    bool ok;
    do {
      unsigned v = 1u;
      if (tid < 32) v = __hip_atomic_load(fl + tid, __ATOMIC_RELAXED, __HIP_MEMORY_SCOPE_SYSTEM);
      ok = (__all(v != 0u) != 0);
      if (!ok) __builtin_amdgcn_s_sleep(1);
    } while (!ok);
  }
  __syncthreads();
  asm volatile("" ::: "memory");
}

__device__ __forceinline__ void set_flag(unsigned* __restrict__ fp, int tid){
  asm volatile("s_waitcnt vmcnt(0) lgkmcnt(0)" ::: "memory");
  __syncthreads();
  if (tid == 0)
    __hip_atomic_store(fp, 1u, __ATOMIC_RELAXED, __HIP_MEMORY_SCOPE_SYSTEM);
}

// Stage one 32x512 bf16 h tile (rows br0..br0+31) into LDS (row stride 520).
__device__ __forceinline__ void stage_tile(const unsigned short* __restrict__ src,
                                           short* __restrict__ dst, int br0, int tid){
  unsigned long long u[16];
  #pragma unroll
  for (int i=0;i<8;i++){
    int c = tid + 256*i;          // 2048 chunks: 32 rows x 64 x 16B
    int r = c >> 6, o = c & 63;
    const unsigned long long* p = (const unsigned long long*)(src + (long)(br0 + r)*512 + o*8);
    u[2*i]   = __hip_atomic_load(p,   __ATOMIC_RELAXED, __HIP_MEMORY_SCOPE_SYSTEM);
    u[2*i+1] = __hip_atomic_load(p+1, __ATOMIC_RELAXED, __HIP_MEMORY_SCOPE_SYSTEM);
  }
  #pragma unroll
  for (int i=0;i<8;i++){
    int c = tid + 256*i;
    int r = c >> 6, o = c & 63;
    unsigned long long* q = (unsigned long long*)(dst + r*LSTRIDE + o*8);
    q[0] = u[2*i]; q[1] = u[2*i+1];
  }
}

__global__ __launch_bounds__(256, 1) void k_lstm_all(
    const unsigned short* __restrict__ Mfold, const unsigned short* __restrict__ Whh0,
    const unsigned short* __restrict__ Wih1, const unsigned short* __restrict__ Whh1,
    const float* __restrict__ biasA0, const float* __restrict__ bfold,
    const float* __restrict__ bias1,
    unsigned short* __restrict__ h0b0, unsigned short* __restrict__ h0b1,
    unsigned short* __restrict__ Hs, unsigned* __restrict__ bar)
{
  __shared__ short smem[2*LDS_TILE];     // 66,560 B: tileA | tileB (ex reuses tileA)
  short* ldsA = smem;
  short* ldsB = smem + LDS_TILE;

  int tid = threadIdx.x;
  int L   = blockIdx.x >> 7;             // 0 or 1
  int idx = blockIdx.x & 127;
  int jg = idx & 31, bs = idx >> 5;
  int br0 = bs*32, j0 = jg*16;
  int lane = tid & 63, wave = tid >> 6;
  int l15 = lane & 15, quad = lane >> 4;

  // ---- preload weight B-fragments into registers (once) ----
  const unsigned short* WA = (L==0) ? Mfold : Wih1;
  const unsigned short* WB = (L==0) ? Whh0  : Whh1;
  int gRow = wave*512 + j0 + l15;        // wave = gate
  short8 bfa[16], bfb[16];
  #pragma unroll
  for (int ks=0; ks<16; ks++){
    bfa[ks] = *(const short8*)(WA + (long)gRow*512 + ks*32 + quad*8);
    bfb[ks] = *(const short8*)(WB + (long)gRow*512 + ks*32 + quad*8);
  }

  // ---- preload biases for this thread's (bl, j-pair) ----
  int bl = tid >> 3, jjp = (tid & 7)*2;
  int jglob = j0 + jjp;
  float b0g[4][2], bNg[4][2];
  #pragma unroll
  for (int gg=0; gg<4; gg++)
    #pragma unroll
    for (int q=0; q<2; q++){
      if (L==0){
        b0g[gg][q] = biasA0[gg*512 + jglob + q];
        bNg[gg][q] = bfold [gg*512 + jglob + q];
      } else {
        b0g[gg][q] = bias1 [gg*512 + jglob + q];
        bNg[gg][q] = b0g[gg][q];
      }
    }

  float creg[2] = {0.f, 0.f};
  unsigned short* bufs[2] = {h0b0, h0b1};

  for (int t = 0; t < T_; t++){
    const unsigned short *haP, *hbP; unsigned short* hoP;
    bool hasA, hasB; int p_own, p_oth, p_arr;
    if (L == 0){
      haP = (t>0) ? (Hs + (size_t)(t-1)*BD) : nullptr;   // h1[t-1] via Mfold
      hbP = bufs[t&1];                                    // h0[t-1] (own layer)
      hoP = bufs[(t+1)&1];
      hasA = (t>0); hasB = true;
      p_own = 2*(t-1); p_oth = 2*(t-1)+1; p_arr = 2*t;
    } else {
      haP = bufs[(t+1)&1];                                // h0[t]  (cross layer)
      hbP = (t>0) ? (Hs + (size_t)(t-1)*BD) : nullptr;    // h1[t-1] (own layer)
      hoP = Hs + (size_t)t*BD;
      hasA = true; hasB = (t>0);
      p_own = 2*(t-1)+1; p_oth = 2*t; p_arr = 2*t+1;
    }

    floatx4 acc[2];
    #pragma unroll
    for (int i=0;i<2;i++){ floatx4 z = {0.f,0.f,0.f,0.f}; acc[i] = z; }

    // own-layer tile: wait (usually already set), stage, and COMPUTE now —
    // this half of the matmul overlaps the other layer's critical phase.
    if (hasB){
      if (t > 0) wait_flags(bar + (p_own*4 + bs)*32, tid);
      stage_tile(hbP, ldsB, br0, tid);
      __syncthreads();
      #pragma unroll
      for (int ks=0; ks<16; ks++)
        #pragma unroll
        for (int mt=0; mt<2; mt++){
          short8 a = *(const short8*)(ldsB + (mt*16 + l15)*LSTRIDE + ks*32 + quad*8);
          acc[mt] = __builtin_amdgcn_mfma_f32_16x16x32_bf16(a, bfb[ks], acc[mt], 0,0,0);
        }
    }
    // cross-layer tile: the critical wait; only stage+32 MFMA remain after it.
    if (hasA){
      wait_flags(bar + (p_oth*4 + bs)*32, tid);
      stage_tile(haP, ldsA, br0, tid);
      __syncthreads();
      #pragma unroll
      for (int ks=0; ks<16; ks++)
        #pragma unroll
        for (int mt=0; mt<2; mt++){
          short8 a = *(const short8*)(ldsA + (mt*16 + l15)*LSTRIDE + ks*32 + quad*8);
          acc[mt] = __builtin_amdgcn_mfma_f32_16x16x32_bf16(a, bfa[ks], acc[mt], 0,0,0);
        }
    }
    __syncthreads();

    // gate exchange: ex[gate][bl][jj]  (reuses tileA region)
    float* ex = (float*)smem;
    #pragma unroll
    for (int mt=0; mt<2; mt++)
      #pragma unroll
      for (int r=0; r<4; r++)
        ex[wave*512 + (mt*16 + quad*4 + r)*16 + l15] = acc[mt][r];
    __syncthreads();

    // pointwise: this thread owns (bl, jjp..jjp+1); c in registers
    {
      float h2[2];
      #pragma unroll
      for (int q=0; q<2; q++){
        float bi = (t==0) ? b0g[0][q] : bNg[0][q];
        float bf_ = (t==0) ? b0g[1][q] : bNg[1][q];
        float bg = (t==0) ? b0g[2][q] : bNg[2][q];
        float bo = (t==0) ? b0g[3][q] : bNg[3][q];
        float gi = ex[0*512 + bl*16 + jjp+q] + bi;
        float gf = ex[1*512 + bl*16 + jjp+q] + bf_;
        float gg = ex[2*512 + bl*16 + jjp+q] + bg;
        float go = ex[3*512 + bl*16 + jjp+q] + bo;
        float ig = sigm(gi), fg = sigm(gf), gt = tanhf(gg), og = sigm(go);
        float cn = fg*creg[q] + ig*gt;
        creg[q] = cn;
        h2[q] = og*tanhf(cn);
      }
      unsigned pack = (unsigned)f2b(h2[0]) | ((unsigned)f2b(h2[1]) << 16);
      __hip_atomic_store((unsigned*)(hoP + (long)(br0 + bl)*512 + jglob), pack,
                         __ATOMIC_RELAXED, __HIP_MEMORY_SCOPE_SYSTEM);
    }
    set_flag(bar + (p_arr*4 + bs)*32 + jg, tid);
  }
}

// Out = Hs (2560x512 bf16) @ Wenc_b^T (+b_enc) -> fp32 (2560x10000)
__global__ __launch_bounds__(256) void k_out_gemm(
    const unsigned short* __restrict__ Ah,
    const unsigned short* __restrict__ Bw,
    const float* __restrict__ b_enc, float* __restrict__ out)
{
  __shared__ short At[128*40];
  __shared__ short Bt[128*40];
  int tid = threadIdx.x;
  int bm = blockIdx.x % 20, bn = blockIdx.x / 20;
  int m0 = bm*128, n0 = bn*128;
  int lane = tid&63, wave = tid>>6, l15 = lane&15, quad = lane>>4;
  int wm = (wave>>1)*64, wn = (wave&1)*64;
  floatx4 acc[4][4];
  #pragma unroll
  for (int i=0;i<4;i++)
    #pragma unroll
    for(int j=0;j<4;j++){ floatx4 z = {0.f,0.f,0.f,0.f}; acc[i][j] = z; }
  for (int k0=0;k0<512;k0+=32){
    #pragma unroll
    for (int i=0;i<2;i++){
      int cc = tid + 256*i; int row = cc>>2; int ko=(cc&3)*8;
      *(short8*)(&At[row*40+ko]) = *(const short8*)(Ah + (long)(m0+row)*512 + k0+ko);
      *(short8*)(&Bt[row*40+ko]) = *(const short8*)(Bw + (long)(n0+row)*512 + k0+ko);
    }
    __syncthreads();
    short8 af[4], bf[4];
    #pragma unroll
    for (int i=0;i<4;i++){
      af[i] = *(const short8*)(&At[(wm + i*16 + l15)*40 + quad*8]);
      bf[i] = *(const short8*)(&Bt[(wn + i*16 + l15)*40 + quad*8]);
    }
    #pragma unroll
    for (int mi=0;mi<4;mi++)
      #pragma unroll
      for (int ni=0;ni<4;ni++)
        acc[mi][ni] = __builtin_amdgcn_mfma_f32_16x16x32_bf16(af[mi],bf[ni],acc[mi][ni],0,0,0);
    __syncthreads();
  }
  #pragma unroll
  for (int mi=0;mi<4;mi++)
    #pragma unroll
    for (int ni=0;ni<4;ni++){
      int n = n0 + wn + ni*16 + l15;
      if (n < V_){
        float be = b_enc[n];
        #pragma unroll
        for (int r=0;r<4;r++){
          int m = m0 + wm + mi*16 + quad*4 + r;
          out[(long)m*V_ + n] = acc[mi][ni][r] + be;
        }
      }
    }
}

extern "C" void kernel_launch(void* const* d_in, const int* in_sizes, int n_in,
                              void* d_out, int out_size, void* d_ws, size_t ws_size,
                              hipStream_t stream){
  const float* input_ = (const float*)d_in[0];
  const float* W_ih0  = (const float*)d_in[1];
  const float* W_hh0  = (const float*)d_in[2];
  const float* b_ih0  = (const float*)d_in[3];
  const float* b_hh0  = (const float*)d_in[4];
  const float* W_ih1  = (const float*)d_in[5];
  const float* W_hh1  = (const float*)d_in[6];
  const float* b_ih1  = (const float*)d_in[7];
  const float* b_hh1  = (const float*)d_in[8];
  const float* W_enc  = (const float*)d_in[9];
  const float* b_enc  = (const float*)d_in[10];
  float* out = (float*)d_out;

  char* ws = (char*)d_ws;
  size_t off = 0;
  auto alloc = [&](size_t bytes){ void* p = ws + off; off += (bytes + 255) & ~255ull; return p; };
  unsigned short* Wenc_b  = (unsigned short*)alloc((size_t)VPAD*512*2);
  unsigned short* WencT_b = (unsigned short*)alloc((size_t)512*KP2*2);
  float*          Mf32    = (float*)alloc((size_t)G4*512*4);
  unsigned short* Mfold_b = (unsigned short*)alloc((size_t)G4*512*2);
  unsigned short* Whh0_b  = (unsigned short*)alloc((size_t)G4*512*2);
  unsigned short* Wih1_b  = (unsigned short*)alloc((size_t)G4*512*2);
  unsigned short* Whh1_b  = (unsigned short*)alloc((size_t)G4*512*2);
  unsigned short* Hs_b    = (unsigned short*)alloc((size_t)T_*BD*2);
  unsigned short* h0b0    = (unsigned short*)alloc((size_t)BD*2);
  unsigned short* h0b1    = (unsigned short*)alloc((size_t)BD*2);
  float* biasA0 = (float*)alloc(2048*4);
  float* bfold  = (float*)alloc(2048*4);
  float* bias1  = (float*)alloc(2048*4);
  unsigned* bar = (unsigned*)alloc((size_t)40*4*32*4);

  k_prep<<<4096, 256, 0, stream>>>(W_hh0, W_ih1, W_hh1, input_, b_ih1, b_hh1,
                                   Whh0_b, Wih1_b, Whh1_b, h0b0, bias1, Mf32, bar);
  k_trans<<<dim3(KP2/64, 512/64), 256, 0, stream>>>(W_enc, Wenc_b, WencT_b);
  k_bias_fold<<<2048, 256, 0, stream>>>(W_ih0, b_enc, b_ih0, b_hh0, biasA0, bfold);
  k_fold_gemm<<<256, 256, 0, stream>>>(W_ih0, WencT_b, Mf32);
  k_convert<<<(G4*512+255)/256, 256, 0, stream>>>(Mf32, Mfold_b, G4*512);

  {
    const unsigned short* a0 = Mfold_b; const unsigned short* a1 = Whh0_b;
    const unsigned short* a2 = Wih1_b; const unsigned short* a3 = Whh1_b;
    const float* a4 = biasA0; const float* a5 = bfold; const float* a6 = bias1;
    unsigned short* a7 = h0b0; unsigned short* a8 = h0b1; unsigned short* a9 = Hs_b;
    unsigned* a10 = bar;
    void* args[] = {&a0,&a1,&a2,&a3,&a4,&a5,&a6,&a7,&a8,&a9,&a10};
    hipLaunchCooperativeKernel((void*)k_lstm_all, dim3(256), dim3(256), args, 0u, stream);
  }

  k_out_gemm<<<20*79, 256, 0, stream>>>(Hs_b, Wenc_b, b_enc, out);
}